// Round 3
// baseline (85.876 us; speedup 1.0000x reference)
//
#include <hip/hip_runtime.h>

// IntraConsistencyLoss — closed-form, j-split, R=4 amortized broadcast version.
//
// Per row (g binary, P positives, Q = W-P):
//   S1 = ordered (pos,pos) sum of |h_i-h_j|,  S2 = mixed,  S3 = (neg,neg)
//   loss = S1/(P^2-P+1) + 1 - S2/(2PQ+1) + S3/(Q^2-Q+1)
// S-sums are linear over j -> split j-range across 2 blocks; every block sees
// all 512 i's so it computes full-row P itself and scales its partial by the
// same denominators before atomicAdd. Exactly one j-half block adds the "+1".

constexpr int NROW = 256;
constexpr int W    = 512;
constexpr int NT   = 128;     // 2 waves; each thread owns 4 consecutive i's
constexpr int JH   = 256;     // j-half length per block

__global__ __launch_bounds__(NT) void icl_kernel(
    const float* __restrict__ a_gt,   const float* __restrict__ s_gt,
    const float* __restrict__ e_gt,   const float* __restrict__ a_heat,
    const float* __restrict__ s_heat, const float* __restrict__ e_heat,
    float* __restrict__ out)
{
    const int row = blockIdx.x;   // 0..255
    const int t   = blockIdx.y;   // 0..2 (a/s/e)
    const int jh  = blockIdx.z;   // 0..1 (j-half)

    const float* gt   = (t == 0) ? a_gt   : (t == 1) ? s_gt   : e_gt;
    const float* heat = (t == 0) ? a_heat : (t == 1) ? s_heat : e_heat;
    gt   += (size_t)row * W;
    heat += (size_t)row * W;

    __shared__ float4 sj4[JH / 2];        // {h0,g0,h1,g1} pairs, 2 KB
    __shared__ float  wred[4][NT / 64];

    const int tid = threadIdx.x;

    // ---- stage this block's j-half as interleaved {h,g} pairs ----
    {
        const int j0 = jh * JH + 2 * tid;           // 128 threads x 2 j's = 256
        const float2 hh = *(const float2*)(heat + j0);
        const float2 gg = *(const float2*)(gt   + j0);
        sj4[tid] = make_float4(hh.x, gg.x, hh.y, gg.y);
    }

    // ---- own i-values: 4 consecutive, coalesced float4 loads ----
    const float4 hi4 = *(const float4*)(heat + 4 * tid);
    const float4 gi4 = *(const float4*)(gt   + 4 * tid);
    const float hi[4] = { hi4.x, hi4.y, hi4.z, hi4.w };
    const float gi[4] = { gi4.x, gi4.y, gi4.z, gi4.w };
    float myP = gi4.x + gi4.y + gi4.z + gi4.w;      // full-row P (block covers all i)

    __syncthreads();

    // ---- pair loop: 1 ds_read_b128 (2 j's) serves 4 i's = 8 pairs ----
    float sa[4] = {0.f, 0.f, 0.f, 0.f};             // sum |h_i - h_j| over this j-half
    float sp[4] = {0.f, 0.f, 0.f, 0.f};             // sum g_j * |h_i - h_j|
    #pragma unroll 4
    for (int k = 0; k < JH / 2; ++k) {
        const float4 v = sj4[k];                    // broadcast, conflict-free
        #pragma unroll
        for (int q = 0; q < 4; ++q) {
            const float d0 = fabsf(hi[q] - v.x);
            sa[q] += d0;
            sp[q]  = fmaf(v.y, d0, sp[q]);
            const float d1 = fabsf(hi[q] - v.z);
            sa[q] += d1;
            sp[q]  = fmaf(v.w, d1, sp[q]);
        }
    }

    // ---- route into S1/S2/S3 by g_i (g exactly 0.0 or 1.0) ----
    float s1 = 0.f, s2 = 0.f, s3 = 0.f;
    #pragma unroll
    for (int q = 0; q < 4; ++q) {
        const float sn = sa[q] - sp[q];
        if (gi[q] > 0.5f) { s1 += sp[q]; s2 += sn; }
        else              { s2 += sp[q]; s3 += sn; }
    }

    // ---- block reduction of {s1, s2, s3, P} over 2 waves ----
    float vals[4] = { s1, s2, s3, myP };
    #pragma unroll
    for (int off = 32; off >= 1; off >>= 1) {
        #pragma unroll
        for (int q = 0; q < 4; ++q)
            vals[q] += __shfl_down(vals[q], off, 64);
    }
    const int lane = tid & 63;
    const int wv   = tid >> 6;
    if (lane == 0) {
        #pragma unroll
        for (int q = 0; q < 4; ++q) wred[q][wv] = vals[q];
    }
    __syncthreads();

    if (tid == 0) {
        float S1 = 0.f, S2 = 0.f, S3 = 0.f, P = 0.f;
        #pragma unroll
        for (int w = 0; w < NT / 64; ++w) {
            S1 += wred[0][w];
            S2 += wred[1][w];
            S3 += wred[2][w];
            P  += wred[3][w];
        }
        const float Q  = (float)W - P;              // P exact integer in fp32
        const float p1 = P * P - P + 1.0f;
        const float p2 = 2.0f * P * Q + 1.0f;
        const float p3 = Q * Q - Q + 1.0f;
        const float part = S1 / p1 - S2 / p2 + S3 / p3 + (jh == 0 ? 1.0f : 0.0f);
        atomicAdd(&out[row], part);                 // 6 adders per row (3t x 2jh)
    }
}

extern "C" void kernel_launch(void* const* d_in, const int* in_sizes, int n_in,
                              void* d_out, int out_size, void* d_ws, size_t ws_size,
                              hipStream_t stream) {
    const float* a_gt   = (const float*)d_in[0];
    const float* s_gt   = (const float*)d_in[1];
    const float* e_gt   = (const float*)d_in[2];
    const float* a_heat = (const float*)d_in[3];
    const float* s_heat = (const float*)d_in[4];
    const float* e_heat = (const float*)d_in[5];
    float* out = (float*)d_out;

    // d_out is re-poisoned to 0xAA before every timed call; zero it for atomics.
    hipMemsetAsync(out, 0, NROW * sizeof(float), stream);

    dim3 grid(NROW, 3, 2);
    icl_kernel<<<grid, NT, 0, stream>>>(a_gt, s_gt, e_gt,
                                        a_heat, s_heat, e_heat, out);
}